// Round 11
// baseline (512.968 us; speedup 1.0000x reference)
//
#include <hip/hip_runtime.h>
#include <hip/hip_bf16.h>
#include <math.h>

#define NB 16
#define NIN 2048
#define NOUT 512
#define TT 1000
#define L_SRM 31

typedef int v4i  __attribute__((ext_vector_type(4)));
typedef int v16i __attribute__((ext_vector_type(16)));

// spread 8 bits -> 8 bytes (0/1) in a u64 (little-endian byte i = bit i)
__device__ __forceinline__ unsigned long long spread8(unsigned int b) {
    unsigned long long x = (unsigned long long)(b & 0xFFu) * 0x0101010101010101ULL;
    x &= 0x8040201008040201ULL;
    x |= x >> 4; x |= x >> 2; x |= x >> 1;
    return x & 0x0101010101010101ULL;
}

// ---------------- kernel 1: quantize W -> 4 signed-i8 planes, o-major --------
__global__ __launch_bounds__(256) void k_quant(const float* __restrict__ W,
                                               signed char* __restrict__ Bq) {
    int idx = blockIdx.x * 256 + threadIdx.x;    // over 512*2048
    int o = idx >> 11, i = idx & (NIN - 1);
    double w = (double)W[o * NIN + i];
    int wq = (int)rint(w * 536870912.0);
    int b0 = (int)(signed char)(wq & 255); int r = (wq - b0) >> 8;
    int b1 = (int)(signed char)(r  & 255); r = (r - b1) >> 8;
    int b2 = (int)(signed char)(r  & 255); r = (r - b2) >> 8;
    int b3 = r;
    size_t e = (size_t)o * NIN + i;
    Bq[e]                = (signed char)b0;
    Bq[e + 1048576]      = (signed char)b1;
    Bq[e + 2097152]      = (signed char)b2;
    Bq[e + 3145728]      = (signed char)b3;
}

// ---------------- kernel 2: ballot-transpose spike extract --------------------
__global__ __launch_bounds__(256) void k_extract(const float* __restrict__ s,
                                                 unsigned long long* __restrict__ bits) {
    __shared__ float tile[64][65];
    int tc = blockIdx.x, ic = blockIdx.y, n = blockIdx.z;
    int t0 = tc * 64, i0 = ic * 64;
    int tid = threadIdx.x;
    int r = tid >> 2, cq = tid & 3;
    const float* rp = s + ((size_t)(n * NIN + i0 + r)) * TT + t0;
    #pragma unroll
    for (int q = 0; q < 4; ++q) {
        int col = cq * 16 + q * 4;
        float4 v = make_float4(0.f, 0.f, 0.f, 0.f);
        if (t0 + col + 3 < TT) v = *(const float4*)(rp + col);
        tile[r][col] = v.x; tile[r][col + 1] = v.y;
        tile[r][col + 2] = v.z; tile[r][col + 3] = v.w;
    }
    __syncthreads();
    int lane = tid & 63, w = tid >> 6;
    #pragma unroll
    for (int k = 0; k < 16; ++k) {
        int tl = w * 16 + k;
        if (t0 + tl >= TT) break;
        unsigned long long m = __ballot(tile[lane][tl] != 0.0f);
        if (lane == 0) bits[((size_t)n * TT + t0 + tl) * 32 + ic] = m;
    }
}

// ---------------- kernel 3: i8-MFMA spike GEMM, 4 exact planes ----------------
__global__ __launch_bounds__(512) void k_spmm(const unsigned long long* __restrict__ bits,
                                              const signed char* __restrict__ Bq,
                                              double* __restrict__ z) {
    __shared__ char Alds[128 * 128];        // 16 KB
    __shared__ char Blds[4][64 * 128];      // 32 KB
    int tid = threadIdx.x;
    int bid = blockIdx.x;                   // 1000
    int o0  = (bid & 7) * 64;
    int nt0 = (bid >> 3) * 128;

    const int arow_w = tid >> 2, q = tid & 3;
    const int p_st = tid >> 7, orow = (tid >> 1) & 63, h = tid & 1;
    const unsigned int* agp = (const unsigned int*)bits + (size_t)(nt0 + arow_w) * 64 + q;
    const signed char*  bgp = Bq + (size_t)p_st * (NOUT * NIN)
                                 + (size_t)(o0 + orow) * NIN + h * 64;
    char* awp = Alds + arow_w * 128;
    const int xra_w = arow_w & 7;
    char* bwp = Blds[p_st] + orow * 128;
    const int xro_w = orow & 7;

    const int l = tid & 63, wv = tid >> 6;
    const int wm = wv >> 1, wn = wv & 1;
    const int arow = wm * 32 + (l & 31), xra = arow & 7;
    const int brow = wn * 32 + (l & 31), xrb = brow & 7;
    const int kg = l >> 5;

    v16i acc0 = {}, acc1 = {}, acc2 = {}, acc3 = {};

    unsigned int aw = agp[0];
    int4 bs0 = ((const int4*)bgp)[0], bs1 = ((const int4*)bgp)[1],
         bs2 = ((const int4*)bgp)[2], bs3 = ((const int4*)bgp)[3];

    for (int ks = 0; ks < 16; ++ks) {
        __syncthreads();
        {
            unsigned long long s0 = spread8(aw), s1 = spread8(aw >> 8),
                               s2 = spread8(aw >> 16), s3 = spread8(aw >> 24);
            ulonglong2 v0; v0.x = s0; v0.y = s1;
            ulonglong2 v1; v1.x = s2; v1.y = s3;
            *(ulonglong2*)(awp + (((2 * q)     ^ xra_w) << 4)) = v0;
            *(ulonglong2*)(awp + (((2 * q + 1) ^ xra_w) << 4)) = v1;
            *(int4*)(bwp + (((h * 4 + 0) ^ xro_w) << 4)) = bs0;
            *(int4*)(bwp + (((h * 4 + 1) ^ xro_w) << 4)) = bs1;
            *(int4*)(bwp + (((h * 4 + 2) ^ xro_w) << 4)) = bs2;
            *(int4*)(bwp + (((h * 4 + 3) ^ xro_w) << 4)) = bs3;
        }
        __syncthreads();
        if (ks < 15) {
            aw = agp[(ks + 1) * 4];
            const int4* g = (const int4*)(bgp + (size_t)(ks + 1) * 128);
            bs0 = g[0]; bs1 = g[1]; bs2 = g[2]; bs3 = g[3];
        }
        #pragma unroll
        for (int ksub = 0; ksub < 4; ++ksub) {
            int ca = ksub * 2 + kg;
            v4i av  = *(const v4i*)(Alds    + arow * 128 + (((ca) ^ xra) << 4));
            v4i bv0 = *(const v4i*)(Blds[0] + brow * 128 + (((ca) ^ xrb) << 4));
            v4i bv1 = *(const v4i*)(Blds[1] + brow * 128 + (((ca) ^ xrb) << 4));
            v4i bv2 = *(const v4i*)(Blds[2] + brow * 128 + (((ca) ^ xrb) << 4));
            v4i bv3 = *(const v4i*)(Blds[3] + brow * 128 + (((ca) ^ xrb) << 4));
            acc0 = __builtin_amdgcn_mfma_i32_32x32x32_i8(av, bv0, acc0, 0, 0, 0);
            acc1 = __builtin_amdgcn_mfma_i32_32x32x32_i8(av, bv1, acc1, 0, 0, 0);
            acc2 = __builtin_amdgcn_mfma_i32_32x32x32_i8(av, bv2, acc2, 0, 0, 0);
            acc3 = __builtin_amdgcn_mfma_i32_32x32x32_i8(av, bv3, acc3, 0, 0, 0);
        }
    }

    #pragma unroll
    for (int r = 0; r < 16; ++r) {
        int row = (r & 3) + 8 * (r >> 2) + 4 * kg;
        long long tot = ((long long)acc3[r] << 24) + ((long long)acc2[r] << 16)
                      + ((long long)acc1[r] << 8)  +  (long long)acc0[r];
        double zv = (double)tot * (1.0 / 536870912.0);
        __builtin_nontemporal_store(zv,
            &z[(size_t)(nt0 + wm * 32 + row) * NOUT + (o0 + wn * 32 + (l & 31))]);
    }
}

// ---------------- kernel 4: temporal conv v2 — async LDS staging --------------
__global__ __launch_bounds__(128) void k_conv(const double* __restrict__ z,
                                              double* __restrict__ wpsp) {
    __shared__ float srm_s[32];
    __shared__ __align__(16) double zs[62 * 128];
    int tid = threadIdx.x;
    if (tid < L_SRM) {
        double t = (double)tid;
        srm_s[tid] = (float)((t / 4.0) * exp(1.0 - t / 4.0));
    }
    int tb = blockIdx.x * 32;
    int oc = blockIdx.y * 128;
    int n  = blockIdx.z;
    const double* zp = z + ((size_t)n * TT) * NOUT + oc;
    int wv = tid >> 6, lane = tid & 63;
    for (int r = wv; r < 62; r += 2) {
        int t = tb - 30 + r;
        if (t >= 0 && t < TT) {
            const double* src = zp + (size_t)t * NOUT + lane * 2;
            __builtin_amdgcn_global_load_lds(
                (const __attribute__((address_space(1))) void*)src,
                (__attribute__((address_space(3))) void*)(&zs[r * 128]),
                16, 0, 0);
        } else {
            double2 zero; zero.x = 0.0; zero.y = 0.0;
            *(double2*)(&zs[r * 128 + lane * 2]) = zero;
        }
    }
    asm volatile("s_waitcnt vmcnt(0)" ::: "memory");
    __syncthreads();
    for (int tl = 0; tl < 32; ++tl) {
        int t = tb + tl;
        if (t >= TT) break;
        double a0 = 0., a1 = 0., a2 = 0., a3 = 0.;
        #pragma unroll
        for (int jj = 0; jj < 28; jj += 4) {
            a0 += (double)srm_s[jj]     * zs[(tl + 30 - jj) * 128 + tid];
            a1 += (double)srm_s[jj + 1] * zs[(tl + 29 - jj) * 128 + tid];
            a2 += (double)srm_s[jj + 2] * zs[(tl + 28 - jj) * 128 + tid];
            a3 += (double)srm_s[jj + 3] * zs[(tl + 27 - jj) * 128 + tid];
        }
        a0 += (double)srm_s[28] * zs[(tl + 2) * 128 + tid];
        a1 += (double)srm_s[29] * zs[(tl + 1) * 128 + tid];
        a2 += (double)srm_s[30] * zs[(tl + 0) * 128 + tid];
        wpsp[((size_t)n * TT + t) * NOUT + oc + tid] = (a0 + a1) + (a2 + a3);
    }
}

// ---------------- kernel 5: spike scan v5 — 2-lane split + 2-deep pipeline ----
// 256 blocks x 1 wave; 32 traces/wave, lanes l and l^32 co-own trace (lane&31).
// Table lookups split across the pair (g=lane>>5): g0 reads T1,T2,T3,T7;
// g1 reads T4,T5,T6. One f64 shfl_xor(32) butterfly merges the halves; f64
// add is commutative so both partners compute bit-identical u (lockstep h).
// Candidate/x reads are pair-broadcast (same addr). Speculative 2-deep
// timeline identical to v4; only sum association differs (~1e-14).
__global__ __launch_bounds__(64) void k_scan(const double* __restrict__ wpsp,
                                             float* __restrict__ out) {
    __shared__ float  refTab[64];
    __shared__ double Tb[8][256];                       // 16 KB
    __shared__ __align__(16) double xbuf[2][34 * 32];   // 32 rows + 2 pad rows
    __shared__ float  obuf[32 * 33];
    int lane = threadIdx.x;
    {
        double d = (double)lane;
        refTab[lane] = (lane == 0) ? 0.0f
                     : (float)(-20.0 * (d / 4.0) * exp(1.0 - d / 4.0));
    }
    __syncthreads();
    for (int e = lane; e < 2048; e += 64) {
        int k = e >> 8, m = e & 255;
        double s = 0.0;
        #pragma unroll
        for (int j = 0; j < 8; ++j) {
            int idx = 8 * k + j + 1;
            if (((m >> j) & 1) && idx <= 63) s += (double)refTab[idx];
        }
        Tb[k][m] = s;
    }

    int n  = blockIdx.x >> 4;                  // 16
    int o0 = (blockIdx.x & 15) << 5;           // 16 chunks of 32 outputs
    int ol = lane & 31;                        // trace within chunk
    int g  = lane >> 5;                        // pair role
    const double* wp = wpsp + ((size_t)n * TT) * NOUT + o0;
    float* op = out + ((size_t)(n * NOUT) + o0 + ol) * TT;
    const double* Tb0 = &Tb[0][0];
    // per-lane table-slot shifts/indices
    const int kA = 1 + 3 * g, kB = 2 + 3 * g, kC = 3 + 3 * g;
    const int shA = 8 + 24 * g, shB = 16 + 24 * g, shC = 24 + 24 * g;

    // stage nrows rows (32 f64 = 256B each): 4 rows per 1KB issue
    #define STAGE(bf, tb, nrows)                                                   \
        for (int p = 0; p < (nrows) / 4; ++p) {                                    \
            const double* src = wp + (size_t)((tb) + 4 * p + (lane >> 4)) * NOUT   \
                                   + (lane & 15) * 2;                              \
            __builtin_amdgcn_global_load_lds(                                      \
                (const __attribute__((address_space(1))) void*)src,                \
                (__attribute__((address_space(3))) void*)(&xbuf[bf][p * 128]),     \
                16, 0, 0);                                                         \
        }

    int buf = 0;
    STAGE(0, 0, 32);
    asm volatile("s_waitcnt vmcnt(0)" ::: "memory");
    __syncthreads();

    unsigned long long h = 0ULL;        // committed spike history (per trace)
    bool sp1 = false;                   // spike at t-1
    double xp = xbuf[0][ol];            // x_0 + partial_0(=0)
    double x1 = xbuf[0][32 + ol];       // x_1
    double partial1 = 0.0;
    double pA = 0., pB = 0., pC = 0., pE = 0.;   // this lane's table loads
    double e0 = 0.0, e1 = 0.0;                   // step-0 candidate pair
    double c1_0 = Tb0[0], c1_1 = Tb0[1], c1_2 = Tb0[2], c1_3 = Tb0[3];

    for (int tb = 0; tb < TT; tb += 32) {
        int nnext = TT - (tb + 32); if (nnext > 32) nnext = 32;
        if (nnext > 0) { STAGE(buf ^ 1, tb + 32, nnext); }
        #pragma unroll
        for (int tl = 0; tl < 32; ++tl) {
            // commit sp_{t-1}
            h = (h << 1) | (unsigned long long)sp1;
            unsigned long long hs = h << 2;     // step t+2 view; bits 0,1 = 0
            // speculative loads for step t+2 (consumed at t+2)
            double tA = Tb[kA][(unsigned)((hs >> shA) & 255)];
            double tB = Tb[kB][(unsigned)((hs >> shB) & 255)];
            double tC = Tb[kC][(unsigned)((hs >> shC) & 255)];
            double tE = Tb[7][(unsigned)((hs >> 56) & 255)];   // pair-broadcast
            double nx = xbuf[buf][(tl + 2) * 32 + ol];          // pair-broadcast
            unsigned m = (unsigned)(hs & 255);
            double2 nc01 = *(const double2*)(Tb0 + m);
            double2 nc23 = *(const double2*)(Tb0 + m + 2);
            // fold step-(t+1) candidates by sp_{t-1} (off critical path)
            double e0n = sp1 ? c1_2 : c1_0;
            double e1n = sp1 ? c1_3 : c1_1;
            // butterfly partial for step t+1 from loads at t-1
            double loc = (pA + pB) + (pC + (g ? 0.0 : pE));
            double np1 = loc + __shfl_xor(loc, 32);
            // resolve step t (critical chain: cndmask + add + cmp)
            double u = xp + (sp1 ? e1 : e0);
            bool spt = (u >= 10.0);
            if (g == 0) obuf[ol * 33 + tl] = spt ? 1.0f : 0.0f;
            double nxp = x1 + np1;
            // rotate
            sp1 = spt; e0 = e0n; e1 = e1n; partial1 = np1;
            xp = nxp; x1 = nx;
            pA = tA; pB = tB; pC = tC; pE = tE;
            c1_0 = nc01.x; c1_1 = nc01.y; c1_2 = nc23.x; c1_3 = nc23.y;
        }
        int nrows = TT - tb; if (nrows > 32) nrows = 32;
        if (g == 0) {
            for (int k = 0; k + 3 < nrows; k += 4) {
                float4 v = make_float4(obuf[ol * 33 + k],     obuf[ol * 33 + k + 1],
                                       obuf[ol * 33 + k + 2], obuf[ol * 33 + k + 3]);
                *(float4*)(op + tb + k) = v;
            }
        }
        asm volatile("s_waitcnt vmcnt(0)" ::: "memory");
        __syncthreads();
        buf ^= 1;
        // repair 2-step x lookahead across the chunk boundary
        xp = xbuf[buf][ol] + partial1;
        x1 = xbuf[buf][32 + ol];
    }
    #undef STAGE
}

extern "C" void kernel_launch(void* const* d_in, const int* in_sizes, int n_in,
                              void* d_out, int out_size, void* d_ws, size_t ws_size,
                              hipStream_t stream) {
    const float* spikeInput = (const float*)d_in[0];   // [16][2048][1000]
    const float* weight     = (const float*)d_in[1];   // [512][2048]
    float* out = (float*)d_out;                        // [16][512][1000]

    char* ws = (char*)d_ws;
    unsigned long long* bits = (unsigned long long*)ws;            //  4,096,000 B
    signed char*        Bq   = (signed char*)(ws + 4194304);       //  4,194,304 B
    double*             z    = (double*)(ws + 8388608);            // 65,536,000 B
    double*             wpsp = (double*)(ws + 73924608);           // 65,536,000 B

    k_quant<<<(NOUT * NIN) / 256, 256, 0, stream>>>(weight, Bq);
    k_extract<<<dim3(16, 32, 16), 256, 0, stream>>>(spikeInput, bits);
    k_spmm<<<1000, 512, 0, stream>>>(bits, Bq, z);
    k_conv<<<dim3(32, 4, 16), 128, 0, stream>>>(z, wpsp);
    k_scan<<<256, 64, 0, stream>>>(wpsp, out);
}

// Round 12
// 482.242 us; speedup vs baseline: 1.0637x; 1.0637x over previous
//
#include <hip/hip_runtime.h>
#include <hip/hip_bf16.h>
#include <math.h>

#define NB 16
#define NIN 2048
#define NOUT 512
#define TT 1000
#define L_SRM 31

typedef int v4i  __attribute__((ext_vector_type(4)));
typedef int v16i __attribute__((ext_vector_type(16)));

// spread 8 bits -> 8 bytes (0/1) in a u64 (little-endian byte i = bit i)
__device__ __forceinline__ unsigned long long spread8(unsigned int b) {
    unsigned long long x = (unsigned long long)(b & 0xFFu) * 0x0101010101010101ULL;
    x &= 0x8040201008040201ULL;
    x |= x >> 4; x |= x >> 2; x |= x >> 1;
    return x & 0x0101010101010101ULL;
}

// ---------------- kernel 1: quantize W -> 4 signed-i8 planes, o-major --------
__global__ __launch_bounds__(256) void k_quant(const float* __restrict__ W,
                                               signed char* __restrict__ Bq) {
    int idx = blockIdx.x * 256 + threadIdx.x;    // over 512*2048
    int o = idx >> 11, i = idx & (NIN - 1);
    double w = (double)W[o * NIN + i];
    int wq = (int)rint(w * 536870912.0);
    int b0 = (int)(signed char)(wq & 255); int r = (wq - b0) >> 8;
    int b1 = (int)(signed char)(r  & 255); r = (r - b1) >> 8;
    int b2 = (int)(signed char)(r  & 255); r = (r - b2) >> 8;
    int b3 = r;
    size_t e = (size_t)o * NIN + i;
    Bq[e]                = (signed char)b0;
    Bq[e + 1048576]      = (signed char)b1;
    Bq[e + 2097152]      = (signed char)b2;
    Bq[e + 3145728]      = (signed char)b3;
}

// ---------------- kernel 2: ballot-transpose spike extract --------------------
__global__ __launch_bounds__(256) void k_extract(const float* __restrict__ s,
                                                 unsigned long long* __restrict__ bits) {
    __shared__ float tile[64][65];
    int tc = blockIdx.x, ic = blockIdx.y, n = blockIdx.z;
    int t0 = tc * 64, i0 = ic * 64;
    int tid = threadIdx.x;
    int r = tid >> 2, cq = tid & 3;
    const float* rp = s + ((size_t)(n * NIN + i0 + r)) * TT + t0;
    #pragma unroll
    for (int q = 0; q < 4; ++q) {
        int col = cq * 16 + q * 4;
        float4 v = make_float4(0.f, 0.f, 0.f, 0.f);
        if (t0 + col + 3 < TT) v = *(const float4*)(rp + col);
        tile[r][col] = v.x; tile[r][col + 1] = v.y;
        tile[r][col + 2] = v.z; tile[r][col + 3] = v.w;
    }
    __syncthreads();
    int lane = tid & 63, w = tid >> 6;
    #pragma unroll
    for (int k = 0; k < 16; ++k) {
        int tl = w * 16 + k;
        if (t0 + tl >= TT) break;
        unsigned long long m = __ballot(tile[lane][tl] != 0.0f);
        if (lane == 0) bits[((size_t)n * TT + t0 + tl) * 32 + ic] = m;
    }
}

// ---------------- kernel 3: i8-MFMA spike GEMM, 4 exact planes ----------------
__global__ __launch_bounds__(512) void k_spmm(const unsigned long long* __restrict__ bits,
                                              const signed char* __restrict__ Bq,
                                              double* __restrict__ z) {
    __shared__ char Alds[128 * 128];        // 16 KB
    __shared__ char Blds[4][64 * 128];      // 32 KB
    int tid = threadIdx.x;
    int bid = blockIdx.x;                   // 1000
    int o0  = (bid & 7) * 64;
    int nt0 = (bid >> 3) * 128;

    const int arow_w = tid >> 2, q = tid & 3;
    const int p_st = tid >> 7, orow = (tid >> 1) & 63, h = tid & 1;
    const unsigned int* agp = (const unsigned int*)bits + (size_t)(nt0 + arow_w) * 64 + q;
    const signed char*  bgp = Bq + (size_t)p_st * (NOUT * NIN)
                                 + (size_t)(o0 + orow) * NIN + h * 64;
    char* awp = Alds + arow_w * 128;
    const int xra_w = arow_w & 7;
    char* bwp = Blds[p_st] + orow * 128;
    const int xro_w = orow & 7;

    const int l = tid & 63, wv = tid >> 6;
    const int wm = wv >> 1, wn = wv & 1;
    const int arow = wm * 32 + (l & 31), xra = arow & 7;
    const int brow = wn * 32 + (l & 31), xrb = brow & 7;
    const int kg = l >> 5;

    v16i acc0 = {}, acc1 = {}, acc2 = {}, acc3 = {};

    unsigned int aw = agp[0];
    int4 bs0 = ((const int4*)bgp)[0], bs1 = ((const int4*)bgp)[1],
         bs2 = ((const int4*)bgp)[2], bs3 = ((const int4*)bgp)[3];

    for (int ks = 0; ks < 16; ++ks) {
        __syncthreads();
        {
            unsigned long long s0 = spread8(aw), s1 = spread8(aw >> 8),
                               s2 = spread8(aw >> 16), s3 = spread8(aw >> 24);
            ulonglong2 v0; v0.x = s0; v0.y = s1;
            ulonglong2 v1; v1.x = s2; v1.y = s3;
            *(ulonglong2*)(awp + (((2 * q)     ^ xra_w) << 4)) = v0;
            *(ulonglong2*)(awp + (((2 * q + 1) ^ xra_w) << 4)) = v1;
            *(int4*)(bwp + (((h * 4 + 0) ^ xro_w) << 4)) = bs0;
            *(int4*)(bwp + (((h * 4 + 1) ^ xro_w) << 4)) = bs1;
            *(int4*)(bwp + (((h * 4 + 2) ^ xro_w) << 4)) = bs2;
            *(int4*)(bwp + (((h * 4 + 3) ^ xro_w) << 4)) = bs3;
        }
        __syncthreads();
        if (ks < 15) {
            aw = agp[(ks + 1) * 4];
            const int4* g = (const int4*)(bgp + (size_t)(ks + 1) * 128);
            bs0 = g[0]; bs1 = g[1]; bs2 = g[2]; bs3 = g[3];
        }
        #pragma unroll
        for (int ksub = 0; ksub < 4; ++ksub) {
            int ca = ksub * 2 + kg;
            v4i av  = *(const v4i*)(Alds    + arow * 128 + (((ca) ^ xra) << 4));
            v4i bv0 = *(const v4i*)(Blds[0] + brow * 128 + (((ca) ^ xrb) << 4));
            v4i bv1 = *(const v4i*)(Blds[1] + brow * 128 + (((ca) ^ xrb) << 4));
            v4i bv2 = *(const v4i*)(Blds[2] + brow * 128 + (((ca) ^ xrb) << 4));
            v4i bv3 = *(const v4i*)(Blds[3] + brow * 128 + (((ca) ^ xrb) << 4));
            acc0 = __builtin_amdgcn_mfma_i32_32x32x32_i8(av, bv0, acc0, 0, 0, 0);
            acc1 = __builtin_amdgcn_mfma_i32_32x32x32_i8(av, bv1, acc1, 0, 0, 0);
            acc2 = __builtin_amdgcn_mfma_i32_32x32x32_i8(av, bv2, acc2, 0, 0, 0);
            acc3 = __builtin_amdgcn_mfma_i32_32x32x32_i8(av, bv3, acc3, 0, 0, 0);
        }
    }

    #pragma unroll
    for (int r = 0; r < 16; ++r) {
        int row = (r & 3) + 8 * (r >> 2) + 4 * kg;
        long long tot = ((long long)acc3[r] << 24) + ((long long)acc2[r] << 16)
                      + ((long long)acc1[r] << 8)  +  (long long)acc0[r];
        double zv = (double)tot * (1.0 / 536870912.0);
        __builtin_nontemporal_store(zv,
            &z[(size_t)(nt0 + wm * 32 + row) * NOUT + (o0 + wn * 32 + (l & 31))]);
    }
}

// ---------------- kernel 4: temporal conv v2 — async LDS staging --------------
__global__ __launch_bounds__(128) void k_conv(const double* __restrict__ z,
                                              double* __restrict__ wpsp) {
    __shared__ float srm_s[32];
    __shared__ __align__(16) double zs[62 * 128];
    int tid = threadIdx.x;
    if (tid < L_SRM) {
        double t = (double)tid;
        srm_s[tid] = (float)((t / 4.0) * exp(1.0 - t / 4.0));
    }
    int tb = blockIdx.x * 32;
    int oc = blockIdx.y * 128;
    int n  = blockIdx.z;
    const double* zp = z + ((size_t)n * TT) * NOUT + oc;
    int wv = tid >> 6, lane = tid & 63;
    for (int r = wv; r < 62; r += 2) {
        int t = tb - 30 + r;
        if (t >= 0 && t < TT) {
            const double* src = zp + (size_t)t * NOUT + lane * 2;
            __builtin_amdgcn_global_load_lds(
                (const __attribute__((address_space(1))) void*)src,
                (__attribute__((address_space(3))) void*)(&zs[r * 128]),
                16, 0, 0);
        } else {
            double2 zero; zero.x = 0.0; zero.y = 0.0;
            *(double2*)(&zs[r * 128 + lane * 2]) = zero;
        }
    }
    asm volatile("s_waitcnt vmcnt(0)" ::: "memory");
    __syncthreads();
    for (int tl = 0; tl < 32; ++tl) {
        int t = tb + tl;
        if (t >= TT) break;
        double a0 = 0., a1 = 0., a2 = 0., a3 = 0.;
        #pragma unroll
        for (int jj = 0; jj < 28; jj += 4) {
            a0 += (double)srm_s[jj]     * zs[(tl + 30 - jj) * 128 + tid];
            a1 += (double)srm_s[jj + 1] * zs[(tl + 29 - jj) * 128 + tid];
            a2 += (double)srm_s[jj + 2] * zs[(tl + 28 - jj) * 128 + tid];
            a3 += (double)srm_s[jj + 3] * zs[(tl + 27 - jj) * 128 + tid];
        }
        a0 += (double)srm_s[28] * zs[(tl + 2) * 128 + tid];
        a1 += (double)srm_s[29] * zs[(tl + 1) * 128 + tid];
        a2 += (double)srm_s[30] * zs[(tl + 0) * 128 + tid];
        wpsp[((size_t)n * TT + t) * NOUT + oc + tid] = (a0 + a1) + (a2 + a3);
    }
}

// ---------------- kernel 5: spike scan v6 — v4 core, register-ring x, no xbuf -
// 128 blocks x 1 wave; lane owns trace (n, o0+lane). v4's validated 2-deep
// speculative rotation kept VERBATIM; x comes from a depth-8 global->register
// prefetch ring (static indices under unroll-8), spikes batch in a register
// mask and store as 2 float4 per 8 steps. DS ops/step: 11 -> 9; no barriers,
// no vmcnt in the loop. Numerically bit-identical to v4.
__global__ __launch_bounds__(64) void k_scan(const double* __restrict__ wpsp,
                                             float* __restrict__ out) {
    __shared__ float  refTab[64];
    __shared__ double Tb[8][256];                       // 16 KB
    int lane = threadIdx.x;
    {
        double d = (double)lane;
        refTab[lane] = (lane == 0) ? 0.0f
                     : (float)(-20.0 * (d / 4.0) * exp(1.0 - d / 4.0));
    }
    __syncthreads();
    for (int e = lane; e < 2048; e += 64) {
        int k = e >> 8, m = e & 255;
        double s = 0.0;
        #pragma unroll
        for (int j = 0; j < 8; ++j) {
            int idx = 8 * k + j + 1;
            if (((m >> j) & 1) && idx <= 63) s += (double)refTab[idx];
        }
        Tb[k][m] = s;
    }
    __syncthreads();

    int n  = blockIdx.x >> 3;
    int o0 = (blockIdx.x & 7) << 6;
    const double* xsrc = wpsp + ((size_t)n * TT) * NOUT + o0 + lane; // [t]*NOUT
    float* op = out + ((size_t)(n * NOUT) + o0 + lane) * TT;
    const double* Tb0 = &Tb[0][0];

    // prologue: xp = x_0, x1 = x_1, ring xq holds x_2..x_9 (slot = value & 7)
    double xp = xsrc[0];
    double x1 = xsrc[NOUT];
    double xq[8];
    #pragma unroll
    for (int j = 0; j < 8; ++j) xq[(j + 2) & 7] = xsrc[(size_t)(j + 2) * NOUT];

    unsigned long long h = 0ULL;
    bool sp1 = false;
    double p0 = 0., p1 = 0., p2 = 0., p3 = 0., p4 = 0., p5 = 0., p6 = 0.;
    double e0 = 0.0, e1 = 0.0;
    double c1_0 = Tb0[0], c1_1 = Tb0[1], c1_2 = Tb0[2], c1_3 = Tb0[3];

    for (int tb = 0; tb < TT; tb += 8) {
        unsigned omask = 0;
        #pragma unroll
        for (int tl = 0; tl < 8; ++tl) {
            int t = tb + tl;
            // commit sp_{t-1}
            h = (h << 1) | (unsigned long long)sp1;
            unsigned long long hs = h << 2;
            // speculative table loads (consumed 2 iters later)
            double q1 = Tb[1][(unsigned)((hs >>  8) & 255)];
            double q2 = Tb[2][(unsigned)((hs >> 16) & 255)];
            double q3 = Tb[3][(unsigned)((hs >> 24) & 255)];
            double q4 = Tb[4][(unsigned)((hs >> 32) & 255)];
            double q5 = Tb[5][(unsigned)((hs >> 40) & 255)];
            double q6 = Tb[6][(unsigned)((hs >> 48) & 255)];
            double q7 = Tb[7][(unsigned)((hs >> 56) & 255)];
            unsigned m = (unsigned)(hs & 255);      // bits 0,1 clear -> 32B aligned
            double2 nc01 = *(const double2*)(Tb0 + m);
            double2 nc23 = *(const double2*)(Tb0 + m + 2);
            // x_{t+2} from the register ring; refill slot with x_{t+10}
            double nx = xq[(tl + 2) & 7];
            int tload = t + 10; if (tload > TT - 1) tload = TT - 1;
            xq[(tl + 2) & 7] = xsrc[(size_t)tload * NOUT];
            // fold step-(t+1) candidates by sp_{t-1}
            double e0n = sp1 ? c1_2 : c1_0;
            double e1n = sp1 ? c1_3 : c1_1;
            // partial from loads 2 iters ago (same association as v4)
            double np1 = ((p0 + p1) + (p2 + p3)) + ((p4 + p5) + p6);
            // resolve step t
            double u = xp + (sp1 ? e1 : e0);
            bool spt = (u >= 10.0);
            omask |= ((unsigned)spt) << tl;
            double nxp = x1 + np1;
            // rotate
            sp1 = spt; e0 = e0n; e1 = e1n;
            xp = nxp; x1 = nx;
            p0 = q1; p1 = q2; p2 = q3; p3 = q4; p4 = q5; p5 = q6; p6 = q7;
            c1_0 = nc01.x; c1_1 = nc01.y; c1_2 = nc23.x; c1_3 = nc23.y;
        }
        float4 v0, v1;
        v0.x = (omask & 1u)   ? 1.0f : 0.0f;  v0.y = (omask & 2u)   ? 1.0f : 0.0f;
        v0.z = (omask & 4u)   ? 1.0f : 0.0f;  v0.w = (omask & 8u)   ? 1.0f : 0.0f;
        v1.x = (omask & 16u)  ? 1.0f : 0.0f;  v1.y = (omask & 32u)  ? 1.0f : 0.0f;
        v1.z = (omask & 64u)  ? 1.0f : 0.0f;  v1.w = (omask & 128u) ? 1.0f : 0.0f;
        *(float4*)(op + tb)     = v0;
        *(float4*)(op + tb + 4) = v1;
    }
}

extern "C" void kernel_launch(void* const* d_in, const int* in_sizes, int n_in,
                              void* d_out, int out_size, void* d_ws, size_t ws_size,
                              hipStream_t stream) {
    const float* spikeInput = (const float*)d_in[0];   // [16][2048][1000]
    const float* weight     = (const float*)d_in[1];   // [512][2048]
    float* out = (float*)d_out;                        // [16][512][1000]

    char* ws = (char*)d_ws;
    unsigned long long* bits = (unsigned long long*)ws;            //  4,096,000 B
    signed char*        Bq   = (signed char*)(ws + 4194304);       //  4,194,304 B
    double*             z    = (double*)(ws + 8388608);            // 65,536,000 B
    double*             wpsp = (double*)(ws + 73924608);           // 65,536,000 B

    k_quant<<<(NOUT * NIN) / 256, 256, 0, stream>>>(weight, Bq);
    k_extract<<<dim3(16, 32, 16), 256, 0, stream>>>(spikeInput, bits);
    k_spmm<<<1000, 512, 0, stream>>>(bits, Bq, z);
    k_conv<<<dim3(32, 4, 16), 128, 0, stream>>>(z, wpsp);
    k_scan<<<128, 64, 0, stream>>>(wpsp, out);
}